// Round 5
// baseline (998.798 us; speedup 1.0000x reference)
//
#include <hip/hip_runtime.h>

// RStarcoderAttention: MoE-LoRA QKV proj + RoPE + causal flash attention + LoRA out proj.
// B=2 S=2048 E=2048 H=16 D=128 NE=8 R=16. fp32 accumulation everywhere.
// Round 5: flash w/ intra-block causal pairing (uniform 34 chunks/block) + reg
// prefetch; fused qkv LoRA-h (N=384); W/Bm converted inline in GEMM B-staging;
// 12 dispatches. Inputs runtime-detected fp32/bf16.

#define B_ 2
#define S_ 2048
#define E_ 2048
#define H_ 16
#define D_ 128
#define NE_ 8
#define R_ 16
#define HD_ 2048
#define M_ 4096          // B*S tokens
#define KL_ 128          // NE*R

typedef unsigned short u16;
typedef unsigned int u32;
typedef __attribute__((ext_vector_type(8))) short bf16x8;
typedef __attribute__((ext_vector_type(4))) float f32x4;

typedef const __attribute__((address_space(1))) void gvoid_t;
typedef __attribute__((address_space(3))) void svoid_t;

__device__ __forceinline__ float bf2f(u16 u) {
    union { u32 i; float f; } v; v.i = ((u32)u) << 16; return v.f;
}
__device__ __forceinline__ u16 f2bf(float f) {
    union { float f; u32 i; } v; v.f = f;
    u32 x = v.i;
    return (u16)((x + 0x7fffu + ((x >> 16) & 1u)) >> 16);   // RNE
}
__device__ __forceinline__ float ldf(const void* p, size_t i, int f) {
    return f ? ((const float*)p)[i] : bf2f(((const u16*)p)[i]);
}
__device__ __forceinline__ float4 ld4(const void* p, size_t i, int f) {
    if (f) return *(const float4*)((const float*)p + i);
    ushort4 v = *(const ushort4*)((const u16*)p + i);
    return make_float4(bf2f(v.x), bf2f(v.y), bf2f(v.z), bf2f(v.w));
}

// ---------------------------------------------------------------------------
__global__ void k_detect(const void* __restrict__ x, int* __restrict__ flags) {
    __shared__ int votes[2];
    int tid = threadIdx.x;
    if (tid < 2) votes[tid] = 0;
    __syncthreads();
    const u32* p = (const u32*)x;
    int bad = 0, tot = 0;
    for (int i = tid; i < 4096; i += 64) {
        u32 lo = p[i] & 0xffffu;
        if (lo) {
            tot++;
            int e = (int)((lo >> 7) & 0xffu);
            if (e < 100 || e > 150) bad++;
        }
    }
    atomicAdd(&votes[0], bad);
    atomicAdd(&votes[1], tot);
    __syncthreads();
    if (tid == 0) flags[0] = (votes[1] > 0 && votes[0] * 10 > votes[1] * 3) ? 1 : 0;
}

// ---------------------------------------------------------------------------
// One-shot conversion: x (8M el) -> Xb, Aq/Ak/Av/Ao (4 x 256K el) -> Acat.
#define NX_ (M_ * E_)          // 8388608
#define NA1_ (KL_ * E_)        // 262144
__global__ void k_cvt_all(const void* __restrict__ x,
                          const void* __restrict__ Aq, const void* __restrict__ Ak,
                          const void* __restrict__ Av, const void* __restrict__ Ao,
                          u16* __restrict__ Xb, u16* __restrict__ Acat,
                          const int* __restrict__ flags) {
    int fin = flags[0];
    long i = (long)(blockIdx.x * 256 + threadIdx.x) * 4;
    const void* src; u16* dst; long off;
    if (i < NX_) { src = x; dst = Xb; off = i; }
    else {
        long j = i - NX_;
        int p = (int)(j >> 18);
        off = j & (NA1_ - 1);
        src = (p == 0) ? Aq : (p == 1) ? Ak : (p == 2) ? Av : Ao;
        dst = Acat + (long)p * NA1_;
    }
    float4 v = ld4(src, off, fin);
    ushort4 o;
    o.x = f2bf(v.x); o.y = f2bf(v.y); o.z = f2bf(v.z); o.w = f2bf(v.w);
    *(ushort4*)(dst + off) = o;
}

// ---------------------------------------------------------------------------
// MFMA GEMM: C[m][n] = sum_k A[m][k]*B[n][k] (+ lora seg) (+bias[n]) (*mask).
// A/A2 bf16 (global_load_lds). B/B2 dtype = b_is_input ? fin : bf16; fp32 B is
// converted inline in staging. 128x128 tile, 4 waves 2x2, BK=64.
#define BM_ 128
#define BN_ 128
#define BK_ 64

__global__ __launch_bounds__(256, 2) void k_gemm_mfma(
    const u16* __restrict__ A, int lda,
    const void* __restrict__ Bw, int ldb, int K1,
    const u16* __restrict__ A2, int lda2,
    const void* __restrict__ B2, int K2,
    const void* __restrict__ bias, const void* __restrict__ mask,
    void* __restrict__ C, int ldc, int store_mode, int b_is_input,
    const int* __restrict__ flags) {
    __shared__ __align__(16) u16 As[BM_ * BK_];   // 16 KB
    __shared__ __align__(16) u16 Bs[BN_ * BK_];   // 16 KB
    int fin = flags[0];
    int bfl = b_is_input ? fin : 0;               // 1 -> B is fp32
    int tid = threadIdx.x;
    int w = tid >> 6, lane = tid & 63;
    int l15 = lane & 15, quad = lane >> 4;
    int wm = w >> 1, wn = w & 1;
    int m0 = blockIdx.y * BM_, n0 = blockIdx.x * BN_;
    int lrow = lane >> 3;          // 0..7
    int lcol = (lane & 7) * 8;     // element offset, 16B granule

    f32x4 acc[4][4];
#pragma unroll
    for (int mt = 0; mt < 4; mt++)
#pragma unroll
        for (int nt = 0; nt < 4; nt++)
#pragma unroll
            for (int r = 0; r < 4; r++) acc[mt][nt][r] = 0.f;

    int n1 = K1 / BK_, n2 = K2 / BK_;
    int total = n1 + n2;
    for (int it = 0; it < total; it++) {
        const u16* pa; const void* pb; int sa, sb, kb;
        if (it < n1) { pa = A;  sa = lda;  pb = Bw; sb = ldb; kb = it * BK_; }
        else         { pa = A2; sa = lda2; pb = B2; sb = K2;  kb = (it - n1) * BK_; }
        __syncthreads();
#pragma unroll
        for (int i = 0; i < 4; i++) {
            int rowb = (w * 4 + i) * 8;
            int r = rowb + lrow;
            __builtin_amdgcn_global_load_lds(
                (gvoid_t*)(pa + (size_t)(m0 + r) * sa + kb + lcol),
                (svoid_t*)(As + rowb * BK_), 16, 0, 0);
        }
        if (!bfl) {
#pragma unroll
            for (int i = 0; i < 4; i++) {
                int rowb = (w * 4 + i) * 8;
                int r = rowb + lrow;
                __builtin_amdgcn_global_load_lds(
                    (gvoid_t*)((const u16*)pb + (size_t)(n0 + r) * sb + kb + lcol),
                    (svoid_t*)(Bs + rowb * BK_), 16, 0, 0);
            }
        } else {
#pragma unroll
            for (int i = 0; i < 4; i++) {
                int rowb = (w * 4 + i) * 8;
                int r = rowb + lrow;
                const float* src = (const float*)pb + (size_t)(n0 + r) * sb + kb + lcol;
                float4 f0 = *(const float4*)src;
                float4 f1 = *(const float4*)(src + 4);
                union { bf16x8 v; u16 s[8]; } pk;
                pk.s[0] = f2bf(f0.x); pk.s[1] = f2bf(f0.y);
                pk.s[2] = f2bf(f0.z); pk.s[3] = f2bf(f0.w);
                pk.s[4] = f2bf(f1.x); pk.s[5] = f2bf(f1.y);
                pk.s[6] = f2bf(f1.z); pk.s[7] = f2bf(f1.w);
                *(bf16x8*)(Bs + rowb * BK_ + lane * 8) = pk.v;
            }
        }
        __syncthreads();
#pragma unroll
        for (int kk = 0; kk < 2; kk++) {
            int ko = kk * 32 + quad * 8;
            bf16x8 af[4], bf[4];
#pragma unroll
            for (int mt = 0; mt < 4; mt++)
                af[mt] = *(const bf16x8*)(As + (wm * 64 + mt * 16 + l15) * BK_ + ko);
#pragma unroll
            for (int nt = 0; nt < 4; nt++)
                bf[nt] = *(const bf16x8*)(Bs + (wn * 64 + nt * 16 + l15) * BK_ + ko);
#pragma unroll
            for (int mt = 0; mt < 4; mt++)
#pragma unroll
                for (int nt = 0; nt < 4; nt++)
                    acc[mt][nt] = __builtin_amdgcn_mfma_f32_16x16x32_bf16(
                        af[mt], bf[nt], acc[mt][nt], 0, 0, 0);
        }
    }

#pragma unroll
    for (int mt = 0; mt < 4; mt++) {
#pragma unroll
        for (int r = 0; r < 4; r++) {
            int m = m0 + wm * 64 + mt * 16 + quad * 4 + r;
#pragma unroll
            for (int nt = 0; nt < 4; nt++) {
                int n = n0 + wn * 64 + nt * 16 + l15;
                float v = acc[mt][nt][r];
                if (bias) v += ldf(bias, (size_t)n, fin);
                if (mask) v *= ldf(mask, (size_t)m * NE_ + ((n & 127) >> 4), fin);
                int f32out = (store_mode == 2) ? fin : store_mode;
                if (f32out) ((float*)C)[(size_t)m * ldc + n] = v;
                else        ((u16*)C)[(size_t)m * ldc + n] = f2bf(v);
            }
        }
    }
}

// ---------------------------------------------------------------------------
// RoPE in place on Q and K in one launch.
__global__ void k_rope2(u16* __restrict__ Q, u16* __restrict__ K) {
    const int n = M_ * HD_ / 2;
    int idx = blockIdx.x * 256 + threadIdx.x;
    u16* Y = (idx < n) ? Q : K;
    int id = (idx < n) ? idx : idx - n;
    int d2 = id & 63;
    int sh = id >> 6;
    int s = (sh >> 4) & (S_ - 1);
    float inv = powf(10000.f, -(float)d2 * (1.f / 64.f));
    float fr = (float)s * inv;
    float c, sn;
    sincosf(fr, &sn, &c);
    size_t base = ((size_t)sh) << 7;
    float t0 = bf2f(Y[base + d2]);
    float t1 = bf2f(Y[base + d2 + 64]);
    Y[base + d2]      = f2bf(t0 * c - t1 * sn);
    Y[base + d2 + 64] = f2bf(t1 * c + t0 * sn);
}

// ---------------------------------------------------------------------------
// Vb [B,S,H*D] -> Vt [B*H*D, S]
__global__ void k_transpose_v(const u16* __restrict__ Vb, u16* __restrict__ Vt) {
    __shared__ u16 t[32][33];
    int s0 = blockIdx.x * 32;
    int n0 = blockIdx.y * 32;
    int b  = blockIdx.z;
    int tx = threadIdx.x & 31, ty = threadIdx.x >> 5;
#pragma unroll
    for (int r = 0; r < 4; r++)
        t[ty + r * 8][tx] = Vb[((size_t)(b * S_ + s0 + ty + r * 8)) * HD_ + n0 + tx];
    __syncthreads();
#pragma unroll
    for (int r = 0; r < 4; r++)
        Vt[((size_t)(b * HD_ + n0 + ty + r * 8)) * S_ + s0 + tx] = t[tx][ty + r * 8];
}

// ---------------------------------------------------------------------------
// MFMA flash attention with intra-block causal pairing: block x does 128-q tile
// t=x then t=15-x; every block = 34 key-chunks of 64. Register prefetch of next
// chunk's K/V overlaps global latency with compute. Grid (8, 32) = 256 blocks.
#define KS_ST 136
#define VT_ST 72
#define SCALE_ 0.088388347648318447f

__global__ __launch_bounds__(256) void k_flash3(
    const u16* __restrict__ Q, const u16* __restrict__ K,
    const u16* __restrict__ Vt, u16* __restrict__ O) {
    __shared__ __align__(16) u16 Ks[64 * KS_ST];
    __shared__ __align__(16) u16 Vs[128 * VT_ST];
    __shared__ __align__(16) u16 Ps[128 * VT_ST];
    int tid = threadIdx.x;
    int w = tid >> 6, lane = tid & 63;
    int l15 = lane & 15, quad = lane >> 4;
    int bh = blockIdx.y, b = bh >> 4, h = bh & 15;

    // staging index mapping (same as r4): per it in 0..3
    int krow[4], kd8[4], vd[4], vkg[4];
#pragma unroll
    for (int it = 0; it < 4; it++) {
        int idx = it * 256 + tid;
        krow[it] = idx >> 4; kd8[it] = (idx & 15) * 8;
        vd[it] = idx >> 3;   vkg[it] = (idx & 7) * 8;
    }

    for (int pass = 0; pass < 2; pass++) {
        int t = pass ? (15 - blockIdx.x) : blockIdx.x;
        int q0 = t * 128;

        bf16x8 qf[2][4];
        size_t baseQ = ((size_t)(b * S_ + q0 + w * 32)) * HD_ + h * D_;
#pragma unroll
        for (int mt = 0; mt < 2; mt++)
#pragma unroll
            for (int ks = 0; ks < 4; ks++)
                qf[mt][ks] = *(const bf16x8*)(Q + baseQ + (size_t)(mt * 16 + l15) * HD_ + ks * 32 + quad * 8);

        f32x4 of[2][8];
#pragma unroll
        for (int mt = 0; mt < 2; mt++)
#pragma unroll
            for (int nt = 0; nt < 8; nt++)
#pragma unroll
                for (int r = 0; r < 4; r++) of[mt][nt][r] = 0.f;
        float mrow[2][4], lrow[2][4];
#pragma unroll
        for (int mt = 0; mt < 2; mt++)
#pragma unroll
            for (int r = 0; r < 4; r++) { mrow[mt][r] = -30000.f; lrow[mt][r] = 0.f; }

        int nch = t * 2 + 2;

        // prefetch chunk 0
        bf16x8 kpre[4], vpre[4];
#pragma unroll
        for (int it = 0; it < 4; it++) {
            kpre[it] = *(const bf16x8*)(K + ((size_t)(b * S_ + krow[it])) * HD_ + h * D_ + kd8[it]);
            vpre[it] = *(const bf16x8*)(Vt + ((size_t)(bh * 128 + vd[it])) * S_ + vkg[it]);
        }

        for (int c = 0; c < nch; c++) {
            int k0 = c * 64;
            __syncthreads();                       // prior-chunk LDS reads done
#pragma unroll
            for (int it = 0; it < 4; it++) {
                *(bf16x8*)(Ks + krow[it] * KS_ST + kd8[it]) = kpre[it];
                *(bf16x8*)(Vs + vd[it] * VT_ST + vkg[it]) = vpre[it];
            }
            __syncthreads();
            if (c + 1 < nch) {                     // prefetch next (overlaps compute)
                int k1 = k0 + 64;
#pragma unroll
                for (int it = 0; it < 4; it++) {
                    kpre[it] = *(const bf16x8*)(K + ((size_t)(b * S_ + k1 + krow[it])) * HD_ + h * D_ + kd8[it]);
                    vpre[it] = *(const bf16x8*)(Vt + ((size_t)(bh * 128 + vd[it])) * S_ + k1 + vkg[it]);
                }
            }

            // ---- QK^T
            f32x4 sf[2][4];
#pragma unroll
            for (int mt = 0; mt < 2; mt++)
#pragma unroll
                for (int nt = 0; nt < 4; nt++)
#pragma unroll
                    for (int r = 0; r < 4; r++) sf[mt][nt][r] = 0.f;
#pragma unroll
            for (int ks = 0; ks < 4; ks++) {
                int koff = ks * 32 + quad * 8;
                bf16x8 qa0 = qf[0][ks], qa1 = qf[1][ks];
#pragma unroll
                for (int nt = 0; nt < 4; nt++) {
                    bf16x8 kb = *(const bf16x8*)(Ks + (nt * 16 + l15) * KS_ST + koff);
                    sf[0][nt] = __builtin_amdgcn_mfma_f32_16x16x32_bf16(qa0, kb, sf[0][nt], 0, 0, 0);
                    sf[1][nt] = __builtin_amdgcn_mfma_f32_16x16x32_bf16(qa1, kb, sf[1][nt], 0, 0, 0);
                }
            }

            // ---- online softmax + P->LDS + O rescale
#pragma unroll
            for (int mt = 0; mt < 2; mt++) {
                int rowb = q0 + w * 32 + mt * 16 + quad * 4;
                float al[4];
#pragma unroll
                for (int nt = 0; nt < 4; nt++) {
                    int key = k0 + nt * 16 + l15;
#pragma unroll
                    for (int r = 0; r < 4; r++) {
                        float sv = sf[mt][nt][r] * SCALE_;
                        sf[mt][nt][r] = (key > rowb + r) ? -30000.f : sv;
                    }
                }
#pragma unroll
                for (int r = 0; r < 4; r++) {
                    float cmax = fmaxf(fmaxf(sf[mt][0][r], sf[mt][1][r]),
                                       fmaxf(sf[mt][2][r], sf[mt][3][r]));
                    cmax = fmaxf(cmax, __shfl_xor(cmax, 1, 64));
                    cmax = fmaxf(cmax, __shfl_xor(cmax, 2, 64));
                    cmax = fmaxf(cmax, __shfl_xor(cmax, 4, 64));
                    cmax = fmaxf(cmax, __shfl_xor(cmax, 8, 64));
                    float mnew = fmaxf(mrow[mt][r], cmax);
                    float a = __expf(mrow[mt][r] - mnew);
                    mrow[mt][r] = mnew;
                    al[r] = a;
                    float psum = 0.f;
#pragma unroll
                    for (int nt = 0; nt < 4; nt++) {
                        float p = __expf(sf[mt][nt][r] - mnew);
                        sf[mt][nt][r] = p;
                        psum += p;
                    }
                    psum += __shfl_xor(psum, 1, 64);
                    psum += __shfl_xor(psum, 2, 64);
                    psum += __shfl_xor(psum, 4, 64);
                    psum += __shfl_xor(psum, 8, 64);
                    lrow[mt][r] = lrow[mt][r] * a + psum;
                }
#pragma unroll
                for (int nt = 0; nt < 4; nt++)
#pragma unroll
                    for (int r = 0; r < 4; r++)
                        Ps[(w * 32 + mt * 16 + quad * 4 + r) * VT_ST + nt * 16 + l15] =
                            f2bf(sf[mt][nt][r]);
#pragma unroll
                for (int nt = 0; nt < 8; nt++)
#pragma unroll
                    for (int r = 0; r < 4; r++) of[mt][nt][r] *= al[r];
            }

            // ---- PV (Ps per-wave; no barrier)
#pragma unroll
            for (int ks2 = 0; ks2 < 2; ks2++) {
                int koff = ks2 * 32 + quad * 8;
                bf16x8 pa0 = *(const bf16x8*)(Ps + (w * 32 + l15) * VT_ST + koff);
                bf16x8 pa1 = *(const bf16x8*)(Ps + (w * 32 + 16 + l15) * VT_ST + koff);
#pragma unroll
                for (int nt = 0; nt < 8; nt++) {
                    bf16x8 vb = *(const bf16x8*)(Vs + (nt * 16 + l15) * VT_ST + koff);
                    of[0][nt] = __builtin_amdgcn_mfma_f32_16x16x32_bf16(pa0, vb, of[0][nt], 0, 0, 0);
                    of[1][nt] = __builtin_amdgcn_mfma_f32_16x16x32_bf16(pa1, vb, of[1][nt], 0, 0, 0);
                }
            }
        }

        // ---- epilogue for this tile
#pragma unroll
        for (int mt = 0; mt < 2; mt++) {
            int rowb = q0 + w * 32 + mt * 16 + quad * 4;
#pragma unroll
            for (int r = 0; r < 4; r++) {
                float inv = 1.f / lrow[mt][r];
                size_t base = ((size_t)(b * S_ + rowb + r)) * HD_ + h * D_;
#pragma unroll
                for (int nt = 0; nt < 8; nt++)
                    O[base + nt * 16 + l15] = f2bf(of[mt][nt][r] * inv);
            }
        }
    }
}

// ---------------------------------------------------------------------------
extern "C" void kernel_launch(void* const* d_in, const int* in_sizes, int n_in,
                              void* d_out, int out_size, void* d_ws, size_t ws_size,
                              hipStream_t stream) {
    const void* x    = d_in[0];
    const void* mask = d_in[1];
    const void* Wq = d_in[2];  const void* bq = d_in[3];
    const void* Aq = d_in[4];  const void* Bq = d_in[5];
    const void* Wk = d_in[6];  const void* bk = d_in[7];
    const void* Ak = d_in[8];  const void* Bk = d_in[9];
    const void* Wv = d_in[10]; const void* bv = d_in[11];
    const void* Av = d_in[12]; const void* Bv = d_in[13];
    const void* Wo = d_in[14]; const void* bo = d_in[15];
    const void* Ao = d_in[16]; const void* Bo = d_in[17];

    char* ws = (char*)d_ws;
    const long MB = 1 << 20;
    int* flags = (int*)ws;
    u16* Xb   = (u16*)(ws + 1  * MB);   // 16 MB
    u16* Acat = (u16*)(ws + 17 * MB);   // 2 MB  [512, 2048] (q,k,v,o)
    u16* hg3  = (u16*)(ws + 19 * MB);   // 3 MB  [M, 384]
    u16* hgo  = (u16*)(ws + 22 * MB);   // 1 MB  [M, 128]
    u16* Qb   = (u16*)(ws + 23 * MB);   // 16 MB each
    u16* Kb   = (u16*)(ws + 39 * MB);
    u16* Vb   = (u16*)(ws + 55 * MB);
    u16* Vt   = (u16*)(ws + 71 * MB);   // end 87 MB
    u16* Ob   = Vb;                     // Vb dead after transpose

    k_detect<<<1, 64, 0, stream>>>(x, flags);
    k_cvt_all<<<(NX_ + 4 * NA1_) / 1024, 256, 0, stream>>>(x, Aq, Ak, Av, Ao, Xb, Acat, flags);

    // fused qkv LoRA-h: hg3[m][p*128+er]
    k_gemm_mfma<<<dim3(3, M_ / BM_), 256, 0, stream>>>(
        Xb, E_, Acat, E_, E_, nullptr, 0, nullptr, 0,
        nullptr, mask, hg3, 384, 0, 0, flags);

    // Q/K/V projections (W, Bm converted inline from wire dtype)
    dim3 gg(HD_ / BN_, M_ / BM_);
    k_gemm_mfma<<<gg, 256, 0, stream>>>(Xb, E_, Wq, E_, E_, hg3 + 0,   384, Bq, KL_,
                                        bq, nullptr, Qb, HD_, 0, 1, flags);
    k_gemm_mfma<<<gg, 256, 0, stream>>>(Xb, E_, Wk, E_, E_, hg3 + 128, 384, Bk, KL_,
                                        bk, nullptr, Kb, HD_, 0, 1, flags);
    k_gemm_mfma<<<gg, 256, 0, stream>>>(Xb, E_, Wv, E_, E_, hg3 + 256, 384, Bv, KL_,
                                        bv, nullptr, Vb, HD_, 0, 1, flags);

    k_rope2<<<(M_ * HD_) / 256, 256, 0, stream>>>(Qb, Kb);
    k_transpose_v<<<dim3(S_ / 32, HD_ / 32, B_), 256, 0, stream>>>(Vb, Vt);

    k_flash3<<<dim3(8, 32), 256, 0, stream>>>(Qb, Kb, Vt, Ob);

    // output projection
    k_gemm_mfma<<<dim3(1, M_ / BM_), 256, 0, stream>>>(
        Ob, HD_, Acat + 384 * E_, E_, E_, nullptr, 0, nullptr, 0,
        nullptr, mask, hgo, KL_, 0, 0, flags);
    k_gemm_mfma<<<gg, 256, 0, stream>>>(Ob, HD_, Wo, E_, E_, hgo, KL_, Bo, KL_,
                                        bo, nullptr, d_out, HD_, 2, 1, flags);
}

// Round 6
// 765.348 us; speedup vs baseline: 1.3050x; 1.3050x over previous
//
#include <hip/hip_runtime.h>

// RStarcoderAttention: MoE-LoRA QKV proj + RoPE + causal flash attention + LoRA out proj.
// B=2 S=2048 E=2048 H=16 D=128 NE=8 R=16. fp32 accumulation everywhere.
// Round 6: revert GEMM to pure-bf16 global_load_lds staging (r5 inline cvt was a
// regression); one batched k_cvt_all; flash with 64-q tiles, 1024 blocks heavy-first,
// 44 KB LDS -> 3 blocks/CU. Numerics identical to r4/r5 (absmax 0.3068848).

#define B_ 2
#define S_ 2048
#define E_ 2048
#define H_ 16
#define D_ 128
#define NE_ 8
#define R_ 16
#define HD_ 2048
#define M_ 4096          // B*S tokens
#define KL_ 128          // NE*R

typedef unsigned short u16;
typedef unsigned int u32;
typedef __attribute__((ext_vector_type(8))) short bf16x8;
typedef __attribute__((ext_vector_type(4))) float f32x4;

typedef const __attribute__((address_space(1))) void gvoid_t;
typedef __attribute__((address_space(3))) void svoid_t;

__device__ __forceinline__ float bf2f(u16 u) {
    union { u32 i; float f; } v; v.i = ((u32)u) << 16; return v.f;
}
__device__ __forceinline__ u16 f2bf(float f) {
    union { float f; u32 i; } v; v.f = f;
    u32 x = v.i;
    return (u16)((x + 0x7fffu + ((x >> 16) & 1u)) >> 16);   // RNE
}
__device__ __forceinline__ float ldf(const void* p, size_t i, int f) {
    return f ? ((const float*)p)[i] : bf2f(((const u16*)p)[i]);
}
__device__ __forceinline__ float4 ld4(const void* p, size_t i, int f) {
    if (f) return *(const float4*)((const float*)p + i);
    ushort4 v = *(const ushort4*)((const u16*)p + i);
    return make_float4(bf2f(v.x), bf2f(v.y), bf2f(v.z), bf2f(v.w));
}

// ---------------------------------------------------------------------------
__global__ void k_detect(const void* __restrict__ x, int* __restrict__ flags) {
    __shared__ int votes[2];
    int tid = threadIdx.x;
    if (tid < 2) votes[tid] = 0;
    __syncthreads();
    const u32* p = (const u32*)x;
    int bad = 0, tot = 0;
    for (int i = tid; i < 4096; i += 64) {
        u32 lo = p[i] & 0xffffu;
        if (lo) {
            tot++;
            int e = (int)((lo >> 7) & 0xffu);
            if (e < 100 || e > 150) bad++;
        }
    }
    atomicAdd(&votes[0], bad);
    atomicAdd(&votes[1], tot);
    __syncthreads();
    if (tid == 0) flags[0] = (votes[1] > 0 && votes[0] * 10 > votes[1] * 3) ? 1 : 0;
}

// ---------------------------------------------------------------------------
// Generic fp32/bf16 -> bf16 conversion (4 el/thread).
__global__ void k_cvt(const void* __restrict__ src, u16* __restrict__ dst, int n,
                      const int* __restrict__ flags) {
    int fin = flags[0];
    int i = (blockIdx.x * 256 + threadIdx.x) * 4;
    if (i >= n) return;
    float4 v = ld4(src, i, fin);
    ushort4 o;
    o.x = f2bf(v.x); o.y = f2bf(v.y); o.z = f2bf(v.z); o.w = f2bf(v.w);
    *(ushort4*)(dst + i) = o;
}

// ---------------------------------------------------------------------------
// Batched conversion: x -> Xb; Aq..Ao -> Acat; Bq..Bo -> Bmcat; Wq/Wk/Wv -> Wb's.
#define NX_  8388608L   // M*E
#define NA1_ 262144L    // KL*E (also HD*KL)
#define NW_  4194304L   // E*HD
__global__ void k_cvt_all(
    const void* __restrict__ x,
    const void* __restrict__ Aq, const void* __restrict__ Ak,
    const void* __restrict__ Av, const void* __restrict__ Ao,
    const void* __restrict__ Bq, const void* __restrict__ Bk,
    const void* __restrict__ Bv, const void* __restrict__ Bo,
    const void* __restrict__ Wq, const void* __restrict__ Wk,
    const void* __restrict__ Wv,
    u16* __restrict__ Xb, u16* __restrict__ Acat, u16* __restrict__ Bmcat,
    u16* __restrict__ Wqb, u16* __restrict__ Wkb, u16* __restrict__ Wvb,
    const int* __restrict__ flags) {
    int fin = flags[0];
    long i = (long)(blockIdx.x * 256 + threadIdx.x) * 4;
    const void* src; u16* dst; long off;
    if (i < NX_) { src = x; dst = Xb; off = i; }
    else if (i < NX_ + 4 * NA1_) {
        long j = i - NX_; int p = (int)(j >> 18); off = j & (NA1_ - 1);
        src = (p == 0) ? Aq : (p == 1) ? Ak : (p == 2) ? Av : Ao;
        dst = Acat + (long)p * NA1_;
    } else if (i < NX_ + 8 * NA1_) {
        long j = i - NX_ - 4 * NA1_; int p = (int)(j >> 18); off = j & (NA1_ - 1);
        src = (p == 0) ? Bq : (p == 1) ? Bk : (p == 2) ? Bv : Bo;
        dst = Bmcat + (long)p * NA1_;
    } else {
        long j = i - NX_ - 8 * NA1_; int p = (int)(j / NW_); off = j - (long)p * NW_;
        src = (p == 0) ? Wq : (p == 1) ? Wk : Wv;
        dst = (p == 0) ? Wqb : (p == 1) ? Wkb : Wvb;
    }
    float4 v = ld4(src, off, fin);
    ushort4 o;
    o.x = f2bf(v.x); o.y = f2bf(v.y); o.z = f2bf(v.z); o.w = f2bf(v.w);
    *(ushort4*)(dst + off) = o;
}

// ---------------------------------------------------------------------------
// MFMA GEMM (r4 structure): C[m][n] = sum_k A[m][k]*B[n][k] (+ lora seg)
// (+ bias[n]) (* mask[m][(n&127)>>4]). A,B,A2,B2 bf16; 128x128 tile, BK=64.
#define BM_ 128
#define BN_ 128
#define BK_ 64

__global__ __launch_bounds__(256, 2) void k_gemm_mfma(
    const u16* __restrict__ A, int lda,
    const u16* __restrict__ Bw, int ldb, int K1,
    const u16* __restrict__ A2, int lda2,
    const u16* __restrict__ B2, int K2,
    const void* __restrict__ bias, const void* __restrict__ mask,
    void* __restrict__ C, int ldc, int store_mode,
    const int* __restrict__ flags) {
    __shared__ __align__(16) u16 As[BM_ * BK_];   // 16 KB
    __shared__ __align__(16) u16 Bs[BN_ * BK_];   // 16 KB
    int fin = flags[0];
    int tid = threadIdx.x;
    int w = tid >> 6, lane = tid & 63;
    int l15 = lane & 15, quad = lane >> 4;
    int wm = w >> 1, wn = w & 1;
    int m0 = blockIdx.y * BM_, n0 = blockIdx.x * BN_;
    int lrow = lane >> 3;          // 0..7
    int lcol = (lane & 7) * 8;     // 16B granule

    f32x4 acc[4][4];
#pragma unroll
    for (int mt = 0; mt < 4; mt++)
#pragma unroll
        for (int nt = 0; nt < 4; nt++)
#pragma unroll
            for (int r = 0; r < 4; r++) acc[mt][nt][r] = 0.f;

    int n1 = K1 / BK_, n2 = K2 / BK_;
    int total = n1 + n2;
    for (int it = 0; it < total; it++) {
        const u16 *pa, *pb; int sa, sb, kb;
        if (it < n1) { pa = A;  sa = lda;  pb = Bw; sb = ldb; kb = it * BK_; }
        else         { pa = A2; sa = lda2; pb = B2; sb = K2;  kb = (it - n1) * BK_; }
        __syncthreads();
#pragma unroll
        for (int i = 0; i < 4; i++) {
            int rowb = (w * 4 + i) * 8;
            int r = rowb + lrow;
            __builtin_amdgcn_global_load_lds(
                (gvoid_t*)(pa + (size_t)(m0 + r) * sa + kb + lcol),
                (svoid_t*)(As + rowb * BK_), 16, 0, 0);
            __builtin_amdgcn_global_load_lds(
                (gvoid_t*)(pb + (size_t)(n0 + r) * sb + kb + lcol),
                (svoid_t*)(Bs + rowb * BK_), 16, 0, 0);
        }
        __syncthreads();
#pragma unroll
        for (int kk = 0; kk < 2; kk++) {
            int ko = kk * 32 + quad * 8;
            bf16x8 af[4], bf[4];
#pragma unroll
            for (int mt = 0; mt < 4; mt++)
                af[mt] = *(const bf16x8*)(As + (wm * 64 + mt * 16 + l15) * BK_ + ko);
#pragma unroll
            for (int nt = 0; nt < 4; nt++)
                bf[nt] = *(const bf16x8*)(Bs + (wn * 64 + nt * 16 + l15) * BK_ + ko);
#pragma unroll
            for (int mt = 0; mt < 4; mt++)
#pragma unroll
                for (int nt = 0; nt < 4; nt++)
                    acc[mt][nt] = __builtin_amdgcn_mfma_f32_16x16x32_bf16(
                        af[mt], bf[nt], acc[mt][nt], 0, 0, 0);
        }
    }

#pragma unroll
    for (int mt = 0; mt < 4; mt++) {
#pragma unroll
        for (int r = 0; r < 4; r++) {
            int m = m0 + wm * 64 + mt * 16 + quad * 4 + r;
#pragma unroll
            for (int nt = 0; nt < 4; nt++) {
                int n = n0 + wn * 64 + nt * 16 + l15;
                float v = acc[mt][nt][r];
                if (bias) v += ldf(bias, (size_t)n, fin);
                if (mask) v *= ldf(mask, (size_t)m * NE_ + ((n & 127) >> 4), fin);
                int f32out = (store_mode == 2) ? fin : store_mode;
                if (f32out) ((float*)C)[(size_t)m * ldc + n] = v;
                else        ((u16*)C)[(size_t)m * ldc + n] = f2bf(v);
            }
        }
    }
}

// ---------------------------------------------------------------------------
// RoPE in place on Q and K in one launch.
__global__ void k_rope2(u16* __restrict__ Q, u16* __restrict__ K) {
    const int n = M_ * HD_ / 2;
    int idx = blockIdx.x * 256 + threadIdx.x;
    u16* Y = (idx < n) ? Q : K;
    int id = (idx < n) ? idx : idx - n;
    int d2 = id & 63;
    int sh = id >> 6;
    int s = (sh >> 4) & (S_ - 1);
    float inv = powf(10000.f, -(float)d2 * (1.f / 64.f));
    float fr = (float)s * inv;
    float c, sn;
    sincosf(fr, &sn, &c);
    size_t base = ((size_t)sh) << 7;
    float t0 = bf2f(Y[base + d2]);
    float t1 = bf2f(Y[base + d2 + 64]);
    Y[base + d2]      = f2bf(t0 * c - t1 * sn);
    Y[base + d2 + 64] = f2bf(t1 * c + t0 * sn);
}

// ---------------------------------------------------------------------------
// Vb [B,S,H*D] -> Vt [B*H*D, S]
__global__ void k_transpose_v(const u16* __restrict__ Vb, u16* __restrict__ Vt) {
    __shared__ u16 t[32][33];
    int s0 = blockIdx.x * 32;
    int n0 = blockIdx.y * 32;
    int b  = blockIdx.z;
    int tx = threadIdx.x & 31, ty = threadIdx.x >> 5;
#pragma unroll
    for (int r = 0; r < 4; r++)
        t[ty + r * 8][tx] = Vb[((size_t)(b * S_ + s0 + ty + r * 8)) * HD_ + n0 + tx];
    __syncthreads();
#pragma unroll
    for (int r = 0; r < 4; r++)
        Vt[((size_t)(b * HD_ + n0 + ty + r * 8)) * S_ + s0 + tx] = t[tx][ty + r * 8];
}

// ---------------------------------------------------------------------------
// MFMA flash attention, 64-query tiles. Grid (32, 32), heavy-first (t = 31-x).
// Block = 4 waves; wave w owns rows q0 + w*16. K/V chunks of 64, reg prefetch.
// LDS 44 KB -> 3 blocks/CU. Per-row numerics identical to r5.
#define KS_ST 136
#define VT_ST 72
#define SCALE_ 0.088388347648318447f

__global__ __launch_bounds__(256, 3) void k_flash4(
    const u16* __restrict__ Q, const u16* __restrict__ K,
    const u16* __restrict__ Vt, u16* __restrict__ O) {
    __shared__ __align__(16) u16 Ks[64 * KS_ST];    // 17408 B
    __shared__ __align__(16) u16 Vs[128 * VT_ST];   // 18432 B
    __shared__ __align__(16) u16 Ps[64 * VT_ST];    //  9216 B
    int tid = threadIdx.x;
    int w = tid >> 6, lane = tid & 63;
    int l15 = lane & 15, quad = lane >> 4;
    int bh = blockIdx.y, b = bh >> 4, h = bh & 15;
    int t = 31 - blockIdx.x;                 // heavy tiles dispatched first
    int q0 = t * 64;

    int krow[4], kd8[4], vd[4], vkg[4];
#pragma unroll
    for (int it = 0; it < 4; it++) {
        int idx = it * 256 + tid;
        krow[it] = idx >> 4; kd8[it] = (idx & 15) * 8;
        vd[it] = idx >> 3;   vkg[it] = (idx & 7) * 8;
    }

    // Q A-frags: rows q0 + w*16 + l15
    bf16x8 qf[4];
    size_t baseQ = ((size_t)(b * S_ + q0 + w * 16 + l15)) * HD_ + h * D_;
#pragma unroll
    for (int ks = 0; ks < 4; ks++)
        qf[ks] = *(const bf16x8*)(Q + baseQ + ks * 32 + quad * 8);

    f32x4 of[8];
#pragma unroll
    for (int nt = 0; nt < 8; nt++)
#pragma unroll
        for (int r = 0; r < 4; r++) of[nt][r] = 0.f;
    float mrow[4], lrow[4];
#pragma unroll
    for (int r = 0; r < 4; r++) { mrow[r] = -30000.f; lrow[r] = 0.f; }

    int nch = t + 1;

    bf16x8 kpre[4], vpre[4];
#pragma unroll
    for (int it = 0; it < 4; it++) {
        kpre[it] = *(const bf16x8*)(K + ((size_t)(b * S_ + krow[it])) * HD_ + h * D_ + kd8[it]);
        vpre[it] = *(const bf16x8*)(Vt + ((size_t)(bh * 128 + vd[it])) * S_ + vkg[it]);
    }

    for (int c = 0; c < nch; c++) {
        int k0 = c * 64;
        __syncthreads();
#pragma unroll
        for (int it = 0; it < 4; it++) {
            *(bf16x8*)(Ks + krow[it] * KS_ST + kd8[it]) = kpre[it];
            *(bf16x8*)(Vs + vd[it] * VT_ST + vkg[it]) = vpre[it];
        }
        __syncthreads();
        if (c + 1 < nch) {
            int k1 = k0 + 64;
#pragma unroll
            for (int it = 0; it < 4; it++) {
                kpre[it] = *(const bf16x8*)(K + ((size_t)(b * S_ + k1 + krow[it])) * HD_ + h * D_ + kd8[it]);
                vpre[it] = *(const bf16x8*)(Vt + ((size_t)(bh * 128 + vd[it])) * S_ + k1 + vkg[it]);
            }
        }

        // ---- QK^T: S(16x64) per wave
        f32x4 sf[4];
#pragma unroll
        for (int nt = 0; nt < 4; nt++)
#pragma unroll
            for (int r = 0; r < 4; r++) sf[nt][r] = 0.f;
#pragma unroll
        for (int ks = 0; ks < 4; ks++) {
            int koff = ks * 32 + quad * 8;
            bf16x8 qa = qf[ks];
#pragma unroll
            for (int nt = 0; nt < 4; nt++) {
                bf16x8 kb = *(const bf16x8*)(Ks + (nt * 16 + l15) * KS_ST + koff);
                sf[nt] = __builtin_amdgcn_mfma_f32_16x16x32_bf16(qa, kb, sf[nt], 0, 0, 0);
            }
        }

        // ---- online softmax (rows = q0 + w*16 + quad*4 + r)
        int rowb = q0 + w * 16 + quad * 4;
        float al[4];
#pragma unroll
        for (int nt = 0; nt < 4; nt++) {
            int key = k0 + nt * 16 + l15;
#pragma unroll
            for (int r = 0; r < 4; r++) {
                float sv = sf[nt][r] * SCALE_;
                sf[nt][r] = (key > rowb + r) ? -30000.f : sv;
            }
        }
#pragma unroll
        for (int r = 0; r < 4; r++) {
            float cmax = fmaxf(fmaxf(sf[0][r], sf[1][r]), fmaxf(sf[2][r], sf[3][r]));
            cmax = fmaxf(cmax, __shfl_xor(cmax, 1, 64));
            cmax = fmaxf(cmax, __shfl_xor(cmax, 2, 64));
            cmax = fmaxf(cmax, __shfl_xor(cmax, 4, 64));
            cmax = fmaxf(cmax, __shfl_xor(cmax, 8, 64));
            float mnew = fmaxf(mrow[r], cmax);
            float a = __expf(mrow[r] - mnew);
            mrow[r] = mnew;
            al[r] = a;
            float psum = 0.f;
#pragma unroll
            for (int nt = 0; nt < 4; nt++) {
                float p = __expf(sf[nt][r] - mnew);
                sf[nt][r] = p;
                psum += p;
            }
            psum += __shfl_xor(psum, 1, 64);
            psum += __shfl_xor(psum, 2, 64);
            psum += __shfl_xor(psum, 4, 64);
            psum += __shfl_xor(psum, 8, 64);
            lrow[r] = lrow[r] * a + psum;
        }
#pragma unroll
        for (int nt = 0; nt < 4; nt++)
#pragma unroll
            for (int r = 0; r < 4; r++)
                Ps[(w * 16 + quad * 4 + r) * VT_ST + nt * 16 + l15] = f2bf(sf[nt][r]);
#pragma unroll
        for (int nt = 0; nt < 8; nt++)
#pragma unroll
            for (int r = 0; r < 4; r++) of[nt][r] *= al[r];

        // ---- PV: O(16x128) += P(16x64) . V(64x128)   (Ps per-wave; no barrier)
#pragma unroll
        for (int ks2 = 0; ks2 < 2; ks2++) {
            int koff = ks2 * 32 + quad * 8;
            bf16x8 pa = *(const bf16x8*)(Ps + (w * 16 + l15) * VT_ST + koff);
#pragma unroll
            for (int nt = 0; nt < 8; nt++) {
                bf16x8 vb = *(const bf16x8*)(Vs + (nt * 16 + l15) * VT_ST + koff);
                of[nt] = __builtin_amdgcn_mfma_f32_16x16x32_bf16(pa, vb, of[nt], 0, 0, 0);
            }
        }
    }

    // ---- epilogue
    int rowb = q0 + w * 16 + quad * 4;
#pragma unroll
    for (int r = 0; r < 4; r++) {
        float inv = 1.f / lrow[r];
        size_t base = ((size_t)(b * S_ + rowb + r)) * HD_ + h * D_;
#pragma unroll
        for (int nt = 0; nt < 8; nt++)
            O[base + nt * 16 + l15] = f2bf(of[nt][r] * inv);
    }
}

// ---------------------------------------------------------------------------
extern "C" void kernel_launch(void* const* d_in, const int* in_sizes, int n_in,
                              void* d_out, int out_size, void* d_ws, size_t ws_size,
                              hipStream_t stream) {
    const void* x    = d_in[0];
    const void* mask = d_in[1];
    const void* Wq = d_in[2];  const void* bq = d_in[3];
    const void* Aq = d_in[4];  const void* Bq = d_in[5];
    const void* Wk = d_in[6];  const void* bk = d_in[7];
    const void* Ak = d_in[8];  const void* Bk = d_in[9];
    const void* Wv = d_in[10]; const void* bv = d_in[11];
    const void* Av = d_in[12]; const void* Bv = d_in[13];
    const void* Wo = d_in[14]; const void* bo = d_in[15];
    const void* Ao = d_in[16]; const void* Bo = d_in[17];

    char* ws = (char*)d_ws;
    const long MB = 1 << 20;
    int* flags = (int*)ws;
    u16* Xb    = (u16*)(ws + 1  * MB);   // 16 MB
    u16* Acat  = (u16*)(ws + 17 * MB);   // 2 MB
    u16* Bmcat = (u16*)(ws + 19 * MB);   // 2 MB
    u16* hg3   = (u16*)(ws + 21 * MB);   // 3 MB  [M,384]
    u16* hgo   = (u16*)(ws + 24 * MB);   // 1 MB  [M,128]
    u16* Qb    = (u16*)(ws + 25 * MB);   // 16 MB; Wo_b reuses 25..33 after flash
    u16* Kb    = (u16*)(ws + 41 * MB);   // 16 MB; Wq_b pre-lives at 41..49
    u16* Vb    = (u16*)(ws + 57 * MB);   // 16 MB; Wk_b pre-lives at 57..65; Ob after
    u16* Vt    = (u16*)(ws + 73 * MB);   // 16 MB; Wv_b pre-lives at 73..81  (end 89 MB)
    u16* Wqb   = Kb;                     // dead before Kb written
    u16* Wkb   = Vb;                     // dead before Vb written
    u16* Wvb   = Vt;                     // dead before Vt written
    u16* Wob   = Qb;                     // converted after flash (Qb dead)
    u16* Ob    = Vb;                     // Vb dead after transpose

    k_detect<<<1, 64, 0, stream>>>(x, flags);
    const long NCVT = NX_ + 8 * NA1_ + 3 * NW_;   // 23068672
    k_cvt_all<<<NCVT / 1024, 256, 0, stream>>>(
        x, Aq, Ak, Av, Ao, Bq, Bk, Bv, Bo, Wq, Wk, Wv,
        Xb, Acat, Bmcat, Wqb, Wkb, Wvb, flags);

    // fused qkv LoRA-h: hg3[m][p*128+er]
    k_gemm_mfma<<<dim3(3, M_ / BM_), 256, 0, stream>>>(
        Xb, E_, Acat, E_, E_, nullptr, 0, nullptr, 0,
        nullptr, mask, hg3, 384, 0, flags);

    dim3 gg(HD_ / BN_, M_ / BM_);
    k_gemm_mfma<<<gg, 256, 0, stream>>>(Xb, E_, Wqb, E_, E_, hg3 + 0,   384, Bmcat, KL_,
                                        bq, nullptr, Qb, HD_, 0, flags);
    k_gemm_mfma<<<gg, 256, 0, stream>>>(Xb, E_, Wkb, E_, E_, hg3 + 128, 384, Bmcat + NA1_, KL_,
                                        bk, nullptr, Kb, HD_, 0, flags);
    k_gemm_mfma<<<gg, 256, 0, stream>>>(Xb, E_, Wvb, E_, E_, hg3 + 256, 384, Bmcat + 2 * NA1_, KL_,
                                        bv, nullptr, Vb, HD_, 0, flags);

    k_rope2<<<(M_ * HD_) / 256, 256, 0, stream>>>(Qb, Kb);
    k_transpose_v<<<dim3(S_ / 32, HD_ / 32, B_), 256, 0, stream>>>(Vb, Vt);

    k_flash4<<<dim3(32, 32), 256, 0, stream>>>(Qb, Kb, Vt, Ob);

    // Wo conversion (into dead Qb region), then output projection
    k_cvt<<<NW_ / 1024, 256, 0, stream>>>(Wo, Wob, (int)NW_, flags);
    k_gemm_mfma<<<dim3(1, M_ / BM_), 256, 0, stream>>>(
        Ob, HD_, Acat + 3 * NA1_, E_, E_, nullptr, 0, nullptr, 0,
        nullptr, mask, hgo, KL_, 0, flags);
    k_gemm_mfma<<<gg, 256, 0, stream>>>(Ob, HD_, Wob, E_, E_, hgo, KL_, Bmcat + 3 * NA1_, KL_,
                                        bo, nullptr, d_out, HD_, 2, flags);
}